// Round 16
// baseline (187.348 us; speedup 1.0000x reference)
//
#include <hip/hip_runtime.h>

// CenterShift: out[n,o] = x[n] * (celu(celu((pos_j-pos_i)@w11+b11)@w12+b12) @ w13 + b13)[o]
// N = 2097152, dims 3 -> 16 -> 64 -> 64, fp32 in/out.
//
// Round 16 = r15 (124us best) with ONE change: the f32 LDS bounce is removed;
// MFMA results are stored DIRECTLY in D-layout with non-temporal stores.
// Theory: r9's contiguous-vs-scatter win (+24%) may have been L2
// write-allocate thrash across the 16 strided lines -- which nt now bypasses.
// Each direct store still covers full 64B sectors (4 lanes x 16B per point).
// If the win was TA request fragmentation instead, this regresses and r15
// stands. Bonus: LDS 48 -> 32 KB/block (3 -> 5 co-resident blocks), and the
// per-tile chain loses 16 ds_writes + 16 ds_reads + lgkm waits.
//  - scalar layer-2 (final); 4-tile wave loop + pos prefetch; swizzled h2
//    tile; per-wave LDS; no __syncthreads  [all r15 verbatim]

typedef __attribute__((ext_vector_type(8))) _Float16 f16x8;
typedef __attribute__((ext_vector_type(4))) float f32x4;

#define TILES 4

__device__ __forceinline__ float celu1(float a) {
    return a > 0.0f ? a : __expf(a) - 1.0f;
}

__global__ __launch_bounds__(256) void centershift_kernel(
    const float* __restrict__ x,
    const float* __restrict__ pos_i,
    const float* __restrict__ pos_j,
    const float* __restrict__ w11, const float* __restrict__ b11,
    const float* __restrict__ w12, const float* __restrict__ b12,
    const float* __restrict__ w13, const float* __restrict__ b13,
    float* __restrict__ out, int n)
{
    __shared__ __align__(16) _Float16 h2s[4][64 * 64];  // 8 KB/wave, swizzled

    const int lane = threadIdx.x & 63;
    const int wid  = threadIdx.x >> 6;
    const int g    = lane >> 4;    // 16-lane group 0..3
    const int r16  = lane & 15;

    const int wbase = (blockIdx.x * 4 + wid) * (64 * TILES);
    if (wbase >= n) return;

    char* h2b = (char*)&h2s[wid][0];

    // ---- hoisted fragments (issue first; overlap tile-0 compute) ----
    // layer-3 A = w13^T: A[row = u*16 + r16][k = kh*32 + g*8 + j]
    f16x8 a3[4][2];
#pragma unroll
    for (int u = 0; u < 4; ++u)
#pragma unroll
        for (int kh = 0; kh < 2; ++kh) {
            f16x8 v;
#pragma unroll
            for (int j = 0; j < 8; ++j)
                v[j] = (_Float16)w13[(kh * 32 + g * 8 + j) * 64 + u * 16 + r16];
            a3[u][kh] = v;
        }
    // bias in C/D layout: lane holds o = u*16 + g*4 + rr
    float b3v[4][4];
#pragma unroll
    for (int u = 0; u < 4; ++u) {
        const float4 bv = *reinterpret_cast<const float4*>(b13 + u * 16 + g * 4);
        b3v[u][0] = bv.x; b3v[u][1] = bv.y; b3v[u][2] = bv.z; b3v[u][3] = bv.w;
    }

    // ---- preload tile-0 pos (lane = its own point) ----
    const float* pip = pos_i + 3 * (size_t)(wbase + lane);
    const float* pjp = pos_j + 3 * (size_t)(wbase + lane);
    float3 cpi = *reinterpret_cast<const float3*>(pip);
    float3 cpj = *reinterpret_cast<const float3*>(pjp);

    const int swzW = (lane & 7) << 4;
    const int rowW = lane * 128;
    const int swzR = (r16 & 7) << 4;

#pragma unroll 1
    for (int t = 0; t < TILES; ++t) {
        const int tb = wbase + t * 64;
        if (tb >= n) break;

        const float p0 = cpj.x - cpi.x, p1 = cpj.y - cpi.y, p2 = cpj.z - cpi.z;

        // ---- layer 1: 3 -> 16 ----
        float h1[16];
#pragma unroll
        for (int j = 0; j < 16; ++j) {
            float a = b11[j];
            a = fmaf(p0, w11[j], a);
            a = fmaf(p1, w11[16 + j], a);
            a = fmaf(p2, w11[32 + j], a);
            h1[j] = celu1(a);
        }

        // prefetch next tile's pos (hidden under the compute below)
        if (t + 1 < TILES) {
            cpi = *reinterpret_cast<const float3*>(pip + (t + 1) * 192);
            cpj = *reinterpret_cast<const float3*>(pjp + (t + 1) * 192);
        }

        // ---- layer 2: 16 -> 64 scalar (wave-uniform weights), to swizzled LDS ----
        for (int c = 0; c < 8; ++c) {
            f16x8 v;
#pragma unroll
            for (int j = 0; j < 8; ++j) {
                const int o = c * 8 + j;
                float a = b12[o];
#pragma unroll
                for (int k = 0; k < 16; ++k)
                    a = fmaf(h1[k], w12[k * 64 + o], a);
                v[j] = (_Float16)celu1(a);
            }
            *reinterpret_cast<f16x8*>(h2b + (rowW + ((c * 16) ^ swzW))) = v;
        }

        // ---- layer 3: MFMA -> direct full-sector nt stores (D-layout) ----
#pragma unroll
        for (int t2 = 0; t2 < 4; ++t2) {
            const int pt   = t2 * 16 + r16;
            const int rowR = pt * 128;
            const f16x8 bb0 = *reinterpret_cast<const f16x8*>(h2b + (rowR + ((     g * 16) ^ swzR)));
            const f16x8 bb1 = *reinterpret_cast<const f16x8*>(h2b + (rowR + ((64 + g * 16) ^ swzR)));
            const float xvt = x[tb + pt];          // 1 line, L1 broadcast
            float* optr = out + (size_t)(tb + pt) * 64;
#pragma unroll
            for (int u = 0; u < 4; ++u) {
                f32x4 acc = { b3v[u][0], b3v[u][1], b3v[u][2], b3v[u][3] };
                acc = __builtin_amdgcn_mfma_f32_16x16x32_f16(a3[u][0], bb0, acc, 0, 0, 0);
                acc = __builtin_amdgcn_mfma_f32_16x16x32_f16(a3[u][1], bb1, acc, 0, 0, 0);
                // lane holds out channels o = u*16 + g*4 + {0..3} of point tb+pt;
                // 4 lanes (g fixed, rr 0..3 within lane) cover one 64B sector
                f32x4 o4 = { acc[0] * xvt, acc[1] * xvt, acc[2] * xvt, acc[3] * xvt };
                __builtin_nontemporal_store(o4, reinterpret_cast<f32x4*>(optr + u * 16 + g * 4));
            }
        }
    }
}

extern "C" void kernel_launch(void* const* d_in, const int* in_sizes, int n_in,
                              void* d_out, int out_size, void* d_ws, size_t ws_size,
                              hipStream_t stream) {
    const float* x     = (const float*)d_in[0];
    const float* pos_i = (const float*)d_in[1];
    const float* pos_j = (const float*)d_in[2];
    const float* w11   = (const float*)d_in[3];
    const float* b11   = (const float*)d_in[4];
    const float* w12   = (const float*)d_in[5];
    const float* b12   = (const float*)d_in[6];
    const float* w13   = (const float*)d_in[7];
    const float* b13   = (const float*)d_in[8];
    float* out = (float*)d_out;

    const int n = in_sizes[0];                        // N (x is [N,1])
    const int per_block = 256 * TILES;                // 4 waves x 4 tiles x 64 pts
    const int blocks = (n + per_block - 1) / per_block;
    centershift_kernel<<<blocks, 256, 0, stream>>>(
        x, pos_i, pos_j, w11, b11, w12, b12, w13, b13, out, n);
}

// Round 17
// 173.975 us; speedup vs baseline: 1.0769x; 1.0769x over previous
//
#include <hip/hip_runtime.h>

// CenterShift: out[n,o] = x[n] * (celu(celu((pos_j-pos_i)@w11+b11)@w12+b12) @ w13 + b13)[o]
// N = 2097152, dims 3 -> 16 -> 64 -> 64, fp32 in/out.
//
// Round 17 = r15 (124us best) with ONE change: the f32 bounce (4KB/wave)
// becomes an f16 bounce (2KB/wave, SEPARATE buffer -- not r12's in-place
// aliasing). LDS 48 -> 40 KB/block -> exactly 4 blocks/CU (160KB) vs 3,
// i.e. 12 -> 16 waves/CU, targeting the overlap gap (124 vs ~92us roofline).
// Store path unchanged and settled by r9/r15/r16 A/B/A: LDS bounce ->
// contiguous 1KB-per-instruction NON-TEMPORAL stores (nt alone: -15%;
// removing the bounce: +50% -- both required).
// Cost: 8 extra cvt per lane-group (negligible) + one f16 rounding of the
// output (r12 measured absmax 0.03125, threshold 0.098).
//  - scalar layer-2 final (MFMA-l2 lost 4x); 4-tile wave loop + pos prefetch;
//    swizzled h2 tile; per-wave LDS; no __syncthreads  [r15 verbatim]

typedef __attribute__((ext_vector_type(8))) _Float16 f16x8;
typedef __attribute__((ext_vector_type(4))) float f32x4;

#define TILES 4

__device__ __forceinline__ float celu1(float a) {
    return a > 0.0f ? a : __expf(a) - 1.0f;
}

__global__ __launch_bounds__(256) void centershift_kernel(
    const float* __restrict__ x,
    const float* __restrict__ pos_i,
    const float* __restrict__ pos_j,
    const float* __restrict__ w11, const float* __restrict__ b11,
    const float* __restrict__ w12, const float* __restrict__ b12,
    const float* __restrict__ w13, const float* __restrict__ b13,
    float* __restrict__ out, int n)
{
    __shared__ __align__(16) _Float16 h2s[4][64 * 64];  // 8 KB/wave, swizzled
    __shared__ __align__(16) _Float16 stg[4][1024];     // 2 KB/wave f16 bounce

    const int lane = threadIdx.x & 63;
    const int wid  = threadIdx.x >> 6;
    const int g    = lane >> 4;    // 16-lane group 0..3
    const int r16  = lane & 15;

    const int wbase = (blockIdx.x * 4 + wid) * (64 * TILES);
    if (wbase >= n) return;

    char* h2b  = (char*)&h2s[wid][0];
    char* stgb = (char*)&stg[wid][0];

    // ---- hoisted fragments (issue first; overlap tile-0 compute) ----
    // layer-3 A = w13^T: A[row = u*16 + r16][k = kh*32 + g*8 + j]
    f16x8 a3[4][2];
#pragma unroll
    for (int u = 0; u < 4; ++u)
#pragma unroll
        for (int kh = 0; kh < 2; ++kh) {
            f16x8 v;
#pragma unroll
            for (int j = 0; j < 8; ++j)
                v[j] = (_Float16)w13[(kh * 32 + g * 8 + j) * 64 + u * 16 + r16];
            a3[u][kh] = v;
        }
    // bias in C/D layout: lane holds o = u*16 + g*4 + rr
    float b3v[4][4];
#pragma unroll
    for (int u = 0; u < 4; ++u) {
        const float4 bv = *reinterpret_cast<const float4*>(b13 + u * 16 + g * 4);
        b3v[u][0] = bv.x; b3v[u][1] = bv.y; b3v[u][2] = bv.z; b3v[u][3] = bv.w;
    }

    // ---- preload tile-0 pos (lane = its own point) ----
    const float* pip = pos_i + 3 * (size_t)(wbase + lane);
    const float* pjp = pos_j + 3 * (size_t)(wbase + lane);
    float3 cpi = *reinterpret_cast<const float3*>(pip);
    float3 cpj = *reinterpret_cast<const float3*>(pjp);

    const int swzW = (lane & 7) << 4;
    const int rowW = lane * 128;
    const int swzR = (r16 & 7) << 4;

#pragma unroll 1
    for (int t = 0; t < TILES; ++t) {
        const int tb = wbase + t * 64;
        if (tb >= n) break;

        const float p0 = cpj.x - cpi.x, p1 = cpj.y - cpi.y, p2 = cpj.z - cpi.z;

        // ---- layer 1: 3 -> 16 ----
        float h1[16];
#pragma unroll
        for (int j = 0; j < 16; ++j) {
            float a = b11[j];
            a = fmaf(p0, w11[j], a);
            a = fmaf(p1, w11[16 + j], a);
            a = fmaf(p2, w11[32 + j], a);
            h1[j] = celu1(a);
        }

        // prefetch next tile's pos (hidden under the compute below)
        if (t + 1 < TILES) {
            cpi = *reinterpret_cast<const float3*>(pip + (t + 1) * 192);
            cpj = *reinterpret_cast<const float3*>(pjp + (t + 1) * 192);
        }

        // ---- layer 2: 16 -> 64 scalar (wave-uniform weights), to swizzled LDS ----
        for (int c = 0; c < 8; ++c) {
            f16x8 v;
#pragma unroll
            for (int j = 0; j < 8; ++j) {
                const int o = c * 8 + j;
                float a = b12[o];
#pragma unroll
                for (int k = 0; k < 16; ++k)
                    a = fmaf(h1[k], w12[k * 64 + o], a);
                v[j] = (_Float16)celu1(a);
            }
            *reinterpret_cast<f16x8*>(h2b + (rowW + ((c * 16) ^ swzW))) = v;
        }

        // ---- layer 3: MFMA -> f16 bounce -> contiguous 1KB-per-instr nt stores ----
#pragma unroll
        for (int t2 = 0; t2 < 4; ++t2) {
            const int pt   = t2 * 16 + r16;
            const int rowR = pt * 128;
            const f16x8 bb0 = *reinterpret_cast<const f16x8*>(h2b + (rowR + ((     g * 16) ^ swzR)));
            const f16x8 bb1 = *reinterpret_cast<const f16x8*>(h2b + (rowR + ((64 + g * 16) ^ swzR)));
            const float xvt = x[tb + pt];          // 1 line, L1 broadcast
#pragma unroll
            for (int u = 0; u < 4; ++u) {
                f32x4 acc = { b3v[u][0], b3v[u][1], b3v[u][2], b3v[u][3] };
                acc = __builtin_amdgcn_mfma_f32_16x16x32_f16(a3[u][0], bb0, acc, 0, 0, 0);
                acc = __builtin_amdgcn_mfma_f32_16x16x32_f16(a3[u][1], bb1, acc, 0, 0, 0);
                // pack f32 -> f16 (one rounding, ~+0.016 absmax; budget OK)
                union { _Float16 h[4]; unsigned long long v; } pk;
                pk.h[0] = (_Float16)(acc[0] * xvt);
                pk.h[1] = (_Float16)(acc[1] * xvt);
                pk.h[2] = (_Float16)(acc[2] * xvt);
                pk.h[3] = (_Float16)(acc[3] * xvt);
                // bounce byte: row r16 (128B rows), off = u*32+g*8,
                // XOR-swizzled by (r16&15)<<3 (bijective within row pairs;
                // r12-verified numerically)
                const int wb = r16 * 128 + ((u * 32 + g * 8) ^ ((r16 & 15) << 3));
                *reinterpret_cast<unsigned long long*>(stgb + wb) = pk.v;
            }
            // drain: 4 nt store instructions, each one contiguous 1KB chunk
            float* og = out + (size_t)(tb + t2 * 16) * 64;
#pragma unroll
            for (int k = 0; k < 4; ++k) {
                const int ptl = k * 4 + (lane >> 4);   // local point 0..15
                const int rb  = ptl * 128 + (((lane & 15) * 8) ^ ((ptl & 15) << 3));
                union { _Float16 h[4]; unsigned long long v; } pk;
                pk.v = *reinterpret_cast<const unsigned long long*>(stgb + rb);
                f32x4 v4 = { (float)pk.h[0], (float)pk.h[1], (float)pk.h[2], (float)pk.h[3] };
                __builtin_nontemporal_store(v4, reinterpret_cast<f32x4*>(og + k * 256 + lane * 4));
            }
        }
    }
}

extern "C" void kernel_launch(void* const* d_in, const int* in_sizes, int n_in,
                              void* d_out, int out_size, void* d_ws, size_t ws_size,
                              hipStream_t stream) {
    const float* x     = (const float*)d_in[0];
    const float* pos_i = (const float*)d_in[1];
    const float* pos_j = (const float*)d_in[2];
    const float* w11   = (const float*)d_in[3];
    const float* b11   = (const float*)d_in[4];
    const float* w12   = (const float*)d_in[5];
    const float* b12   = (const float*)d_in[6];
    const float* w13   = (const float*)d_in[7];
    const float* b13   = (const float*)d_in[8];
    float* out = (float*)d_out;

    const int n = in_sizes[0];                        // N (x is [N,1])
    const int per_block = 256 * TILES;                // 4 waves x 4 tiles x 64 pts
    const int blocks = (n + per_block - 1) / per_block;
    centershift_kernel<<<blocks, 256, 0, stream>>>(
        x, pos_i, pos_j, w11, b11, w12, b12, w13, b13, out, n);
}

// Round 18
// 135.218 us; speedup vs baseline: 1.3855x; 1.2866x over previous
//
#include <hip/hip_runtime.h>

// CenterShift: out[n,o] = x[n] * (celu(celu((pos_j-pos_i)@w11+b11)@w12+b12) @ w13 + b13)[o]
// N = 2097152, dims 3 -> 16 -> 64 -> 64, fp32 in/out.
//
// Round 18 = r15 (124us best) with ONE structural change: persistent
// grid-stride distribution. 2048 uniform blocks on 768 co-resident slots
// (3 blocks/CU, LDS-capped) = 2.67 rounds -> makespan 3 rounds -> ~12% tail
// idle (~15us). Launch exactly 768 blocks; each wave strides over wave-tiles
// (stride = gridDim.x*4 waves x 64 pts). Imbalance drops to 1 wave-tile
// (10 vs 11 iters ~ 3%); w13-gather prologue amortizes 2.7x more.
// Inner body r15 VERBATIM. Settled invariants:
//  - f32 LDS bounce -> contiguous 1KB-per-instruction NT stores (r9+r15 wins;
//    r16 direct-store refuted; r17 f16-bounce refuted)
//  - scalar layer-2 (MFMA-l2 lost 4x); swizzled h2 tile; pos prefetch;
//    per-wave LDS; no __syncthreads; no extra persistent VGPRs (r11 lesson)

typedef __attribute__((ext_vector_type(8))) _Float16 f16x8;
typedef __attribute__((ext_vector_type(4))) float f32x4;

__device__ __forceinline__ float celu1(float a) {
    return a > 0.0f ? a : __expf(a) - 1.0f;
}

__global__ __launch_bounds__(256) void centershift_kernel(
    const float* __restrict__ x,
    const float* __restrict__ pos_i,
    const float* __restrict__ pos_j,
    const float* __restrict__ w11, const float* __restrict__ b11,
    const float* __restrict__ w12, const float* __restrict__ b12,
    const float* __restrict__ w13, const float* __restrict__ b13,
    float* __restrict__ out, int n)
{
    __shared__ __align__(16) _Float16 h2s[4][64 * 64];  // 8 KB/wave, swizzled
    __shared__ __align__(16) float    stg[4][1024];     // 4 KB/wave bounce

    const int lane = threadIdx.x & 63;
    const int wid  = threadIdx.x >> 6;
    const int g    = lane >> 4;    // 16-lane group 0..3
    const int r16  = lane & 15;

    const int gwave      = blockIdx.x * 4 + wid;        // global wave id
    const int stride_pts = gridDim.x * 4 * 64;          // points per sweep
    int tb = gwave * 64;
    if (tb >= n) return;

    char* h2b  = (char*)&h2s[wid][0];
    char* stgb = (char*)&stg[wid][0];

    // ---- hoisted fragments (issue first; overlap first tile's compute) ----
    // layer-3 A = w13^T: A[row = u*16 + r16][k = kh*32 + g*8 + j]
    f16x8 a3[4][2];
#pragma unroll
    for (int u = 0; u < 4; ++u)
#pragma unroll
        for (int kh = 0; kh < 2; ++kh) {
            f16x8 v;
#pragma unroll
            for (int j = 0; j < 8; ++j)
                v[j] = (_Float16)w13[(kh * 32 + g * 8 + j) * 64 + u * 16 + r16];
            a3[u][kh] = v;
        }
    // bias in C/D layout: lane holds o = u*16 + g*4 + rr
    float b3v[4][4];
#pragma unroll
    for (int u = 0; u < 4; ++u) {
        const float4 bv = *reinterpret_cast<const float4*>(b13 + u * 16 + g * 4);
        b3v[u][0] = bv.x; b3v[u][1] = bv.y; b3v[u][2] = bv.z; b3v[u][3] = bv.w;
    }

    // ---- preload first tile's pos (lane = its own point) ----
    float3 cpi = *reinterpret_cast<const float3*>(pos_i + 3 * (size_t)(tb + lane));
    float3 cpj = *reinterpret_cast<const float3*>(pos_j + 3 * (size_t)(tb + lane));

    const int swzW = (lane & 7) << 4;
    const int rowW = lane * 128;
    const int swzR = (r16 & 7) << 4;

#pragma unroll 1
    for (; tb < n; tb += stride_pts) {
        const float p0 = cpj.x - cpi.x, p1 = cpj.y - cpi.y, p2 = cpj.z - cpi.z;

        // ---- layer 1: 3 -> 16 ----
        float h1[16];
#pragma unroll
        for (int j = 0; j < 16; ++j) {
            float a = b11[j];
            a = fmaf(p0, w11[j], a);
            a = fmaf(p1, w11[16 + j], a);
            a = fmaf(p2, w11[32 + j], a);
            h1[j] = celu1(a);
        }

        // prefetch next iteration's pos (hidden under the compute below)
        {
            const int tn = tb + stride_pts;
            if (tn < n) {
                cpi = *reinterpret_cast<const float3*>(pos_i + 3 * (size_t)(tn + lane));
                cpj = *reinterpret_cast<const float3*>(pos_j + 3 * (size_t)(tn + lane));
            }
        }

        // ---- layer 2: 16 -> 64 scalar (wave-uniform weights), to swizzled LDS ----
        for (int c = 0; c < 8; ++c) {
            f16x8 v;
#pragma unroll
            for (int j = 0; j < 8; ++j) {
                const int o = c * 8 + j;
                float a = b12[o];
#pragma unroll
                for (int k = 0; k < 16; ++k)
                    a = fmaf(h1[k], w12[k * 64 + o], a);
                v[j] = (_Float16)celu1(a);
            }
            *reinterpret_cast<f16x8*>(h2b + (rowW + ((c * 16) ^ swzW))) = v;
        }

        // ---- layer 3: MFMA -> LDS bounce -> contiguous 1KB-per-instr nt stores ----
#pragma unroll
        for (int t2 = 0; t2 < 4; ++t2) {
            const int pt   = t2 * 16 + r16;
            const int rowR = pt * 128;
            const f16x8 bb0 = *reinterpret_cast<const f16x8*>(h2b + (rowR + ((     g * 16) ^ swzR)));
            const f16x8 bb1 = *reinterpret_cast<const f16x8*>(h2b + (rowR + ((64 + g * 16) ^ swzR)));
            const float xvt = x[tb + pt];          // 1 line, L1 broadcast
#pragma unroll
            for (int u = 0; u < 4; ++u) {
                f32x4 acc = { b3v[u][0], b3v[u][1], b3v[u][2], b3v[u][3] };
                acc = __builtin_amdgcn_mfma_f32_16x16x32_f16(a3[u][0], bb0, acc, 0, 0, 0);
                acc = __builtin_amdgcn_mfma_f32_16x16x32_f16(a3[u][1], bb1, acc, 0, 0, 0);
                // lane holds ch c = u*4+g (16B block) of local point r16:
                // bounce byte = r16*256 + ((c*16) ^ ((r16&7)<<4))
                f32x4 o4 = { acc[0] * xvt, acc[1] * xvt, acc[2] * xvt, acc[3] * xvt };
                const int wb = r16 * 256 + (((u * 64 + g * 16)) ^ ((r16 & 7) << 4));
                *reinterpret_cast<f32x4*>(stgb + wb) = o4;
            }
            // drain: 4 instructions, each one contiguous 1KB chunk, non-temporal
            float* og = out + (size_t)(tb + t2 * 16) * 64;
#pragma unroll
            for (int k = 0; k < 4; ++k) {
                const int ptl = k * 4 + (lane >> 4);   // local point 0..15
                const int c   = lane & 15;             // 16B channel block
                const int rb  = ptl * 256 + ((c * 16) ^ ((ptl & 7) << 4));
                const f32x4 v = *reinterpret_cast<const f32x4*>(stgb + rb);
                __builtin_nontemporal_store(v, reinterpret_cast<f32x4*>(og + k * 256 + lane * 4));
            }
        }
    }
}

extern "C" void kernel_launch(void* const* d_in, const int* in_sizes, int n_in,
                              void* d_out, int out_size, void* d_ws, size_t ws_size,
                              hipStream_t stream) {
    const float* x     = (const float*)d_in[0];
    const float* pos_i = (const float*)d_in[1];
    const float* pos_j = (const float*)d_in[2];
    const float* w11   = (const float*)d_in[3];
    const float* b11   = (const float*)d_in[4];
    const float* w12   = (const float*)d_in[5];
    const float* b12   = (const float*)d_in[6];
    const float* w13   = (const float*)d_in[7];
    const float* b13   = (const float*)d_in[8];
    float* out = (float*)d_out;

    const int n = in_sizes[0];                 // N (x is [N,1])
    // persistent: exactly 3 blocks/CU (LDS-capped co-residency), grid-stride
    int blocks = 256 * 3;
    const int max_needed = (n + 255) / 256;    // 1 tile per wave minimum
    if (blocks > max_needed) blocks = max_needed;
    centershift_kernel<<<blocks, 256, 0, stream>>>(
        x, pos_i, pos_j, w11, b11, w12, b12, w13, b13, out, n);
}

// Round 19
// 121.550 us; speedup vs baseline: 1.5413x; 1.1124x over previous
//
#include <hip/hip_runtime.h>

// CenterShift: out[n,o] = x[n] * (celu(celu((pos_j-pos_i)@w11+b11)@w12+b12) @ w13 + b13)[o]
// N = 2097152, dims 3 -> 16 -> 64 -> 64, fp32 in/out.
//
// Round 19 = r15 (124us best, 2048 blocks restored after r18's persistent-grid
// regression) with ONE change: the drain is DEFERRED by one t2 group.
// r15 per-group chain: bounce-write -> lgkm -> drain-read -> lgkm -> nt-store,
// fully serial on the in-order DS pipe. Now: MFMA(t2) ; drain(t2-1) ;
// bounce-write(t2), so each drain's LDS latency hides under the next group's
// MFMAs. Same 4KB buffer is WAR-safe: drain reads are issued in program order
// BEFORE the overwriting bounce writes -> in-order DS returns old data (the
// property r9-r17 all relied on).
// Settled invariants: f32 bounce + contiguous 1KB-per-instr NT stores
// (r9/r15/r16/r17 A/B); scalar layer-2 (MFMA-l2 lost 4x); swizzled h2 tile;
// 4-tile wave loop + pos prefetch; 2048 blocks (scheduler backfills, r18);
// no extra persistent VGPRs (r11); per-wave LDS; no __syncthreads.

typedef __attribute__((ext_vector_type(8))) _Float16 f16x8;
typedef __attribute__((ext_vector_type(4))) float f32x4;

#define TILES 4

__device__ __forceinline__ float celu1(float a) {
    return a > 0.0f ? a : __expf(a) - 1.0f;
}

__global__ __launch_bounds__(256) void centershift_kernel(
    const float* __restrict__ x,
    const float* __restrict__ pos_i,
    const float* __restrict__ pos_j,
    const float* __restrict__ w11, const float* __restrict__ b11,
    const float* __restrict__ w12, const float* __restrict__ b12,
    const float* __restrict__ w13, const float* __restrict__ b13,
    float* __restrict__ out, int n)
{
    __shared__ __align__(16) _Float16 h2s[4][64 * 64];  // 8 KB/wave, swizzled
    __shared__ __align__(16) float    stg[4][1024];     // 4 KB/wave bounce

    const int lane = threadIdx.x & 63;
    const int wid  = threadIdx.x >> 6;
    const int g    = lane >> 4;    // 16-lane group 0..3
    const int r16  = lane & 15;

    const int wbase = (blockIdx.x * 4 + wid) * (64 * TILES);
    if (wbase >= n) return;

    char* h2b  = (char*)&h2s[wid][0];
    char* stgb = (char*)&stg[wid][0];

    // ---- hoisted fragments (issue first; overlap tile-0 compute) ----
    // layer-3 A = w13^T: A[row = u*16 + r16][k = kh*32 + g*8 + j]
    f16x8 a3[4][2];
#pragma unroll
    for (int u = 0; u < 4; ++u)
#pragma unroll
        for (int kh = 0; kh < 2; ++kh) {
            f16x8 v;
#pragma unroll
            for (int j = 0; j < 8; ++j)
                v[j] = (_Float16)w13[(kh * 32 + g * 8 + j) * 64 + u * 16 + r16];
            a3[u][kh] = v;
        }
    // bias in C/D layout: lane holds o = u*16 + g*4 + rr
    float b3v[4][4];
#pragma unroll
    for (int u = 0; u < 4; ++u) {
        const float4 bv = *reinterpret_cast<const float4*>(b13 + u * 16 + g * 4);
        b3v[u][0] = bv.x; b3v[u][1] = bv.y; b3v[u][2] = bv.z; b3v[u][3] = bv.w;
    }

    // ---- preload tile-0 pos (lane = its own point) ----
    const float* pip = pos_i + 3 * (size_t)(wbase + lane);
    const float* pjp = pos_j + 3 * (size_t)(wbase + lane);
    float3 cpi = *reinterpret_cast<const float3*>(pip);
    float3 cpj = *reinterpret_cast<const float3*>(pjp);

    const int swzW = (lane & 7) << 4;
    const int rowW = lane * 128;
    const int swzR = (r16 & 7) << 4;

#pragma unroll 1
    for (int t = 0; t < TILES; ++t) {
        const int tb = wbase + t * 64;
        if (tb >= n) break;

        const float p0 = cpj.x - cpi.x, p1 = cpj.y - cpi.y, p2 = cpj.z - cpi.z;

        // ---- layer 1: 3 -> 16 ----
        float h1[16];
#pragma unroll
        for (int j = 0; j < 16; ++j) {
            float a = b11[j];
            a = fmaf(p0, w11[j], a);
            a = fmaf(p1, w11[16 + j], a);
            a = fmaf(p2, w11[32 + j], a);
            h1[j] = celu1(a);
        }

        // prefetch next tile's pos (hidden under the compute below)
        if (t + 1 < TILES) {
            cpi = *reinterpret_cast<const float3*>(pip + (t + 1) * 192);
            cpj = *reinterpret_cast<const float3*>(pjp + (t + 1) * 192);
        }

        // ---- layer 2: 16 -> 64 scalar (wave-uniform weights), to swizzled LDS ----
        for (int c = 0; c < 8; ++c) {
            f16x8 v;
#pragma unroll
            for (int j = 0; j < 8; ++j) {
                const int o = c * 8 + j;
                float a = b12[o];
#pragma unroll
                for (int k = 0; k < 16; ++k)
                    a = fmaf(h1[k], w12[k * 64 + o], a);
                v[j] = (_Float16)celu1(a);
            }
            *reinterpret_cast<f16x8*>(h2b + (rowW + ((c * 16) ^ swzW))) = v;
        }

        // ---- layer 3: MFMA(t2) ; drain(t2-1) ; bounce-write(t2) ----
#pragma unroll
        for (int t2 = 0; t2 < 4; ++t2) {
            const int pt   = t2 * 16 + r16;
            const int rowR = pt * 128;
            const f16x8 bb0 = *reinterpret_cast<const f16x8*>(h2b + (rowR + ((     g * 16) ^ swzR)));
            const f16x8 bb1 = *reinterpret_cast<const f16x8*>(h2b + (rowR + ((64 + g * 16) ^ swzR)));
            const float xvt = x[tb + pt];          // 1 line, L1 broadcast
            f32x4 o4s[4];
#pragma unroll
            for (int u = 0; u < 4; ++u) {
                f32x4 acc = { b3v[u][0], b3v[u][1], b3v[u][2], b3v[u][3] };
                acc = __builtin_amdgcn_mfma_f32_16x16x32_f16(a3[u][0], bb0, acc, 0, 0, 0);
                acc = __builtin_amdgcn_mfma_f32_16x16x32_f16(a3[u][1], bb1, acc, 0, 0, 0);
                o4s[u][0] = acc[0] * xvt; o4s[u][1] = acc[1] * xvt;
                o4s[u][2] = acc[2] * xvt; o4s[u][3] = acc[3] * xvt;
            }
            // drain PREVIOUS group (reads issued before this group's writes;
            // in-order DS pipe -> returns old data; latency hid under MFMAs)
            if (t2 > 0) {
                float* og = out + (size_t)(tb + (t2 - 1) * 16) * 64;
#pragma unroll
                for (int k = 0; k < 4; ++k) {
                    const int ptl = k * 4 + (lane >> 4);   // local point 0..15
                    const int c   = lane & 15;             // 16B channel block
                    const int rb  = ptl * 256 + ((c * 16) ^ ((ptl & 7) << 4));
                    const f32x4 v = *reinterpret_cast<const f32x4*>(stgb + rb);
                    __builtin_nontemporal_store(v, reinterpret_cast<f32x4*>(og + k * 256 + lane * 4));
                }
            }
            // bounce-write this group (overwrites only after the drain reads)
#pragma unroll
            for (int u = 0; u < 4; ++u) {
                const int wb = r16 * 256 + (((u * 64 + g * 16)) ^ ((r16 & 7) << 4));
                *reinterpret_cast<f32x4*>(stgb + wb) = o4s[u];
            }
        }
        {   // tail drain: group 3
            float* og = out + (size_t)(tb + 3 * 16) * 64;
#pragma unroll
            for (int k = 0; k < 4; ++k) {
                const int ptl = k * 4 + (lane >> 4);
                const int c   = lane & 15;
                const int rb  = ptl * 256 + ((c * 16) ^ ((ptl & 7) << 4));
                const f32x4 v = *reinterpret_cast<const f32x4*>(stgb + rb);
                __builtin_nontemporal_store(v, reinterpret_cast<f32x4*>(og + k * 256 + lane * 4));
            }
        }
    }
}

extern "C" void kernel_launch(void* const* d_in, const int* in_sizes, int n_in,
                              void* d_out, int out_size, void* d_ws, size_t ws_size,
                              hipStream_t stream) {
    const float* x     = (const float*)d_in[0];
    const float* pos_i = (const float*)d_in[1];
    const float* pos_j = (const float*)d_in[2];
    const float* w11   = (const float*)d_in[3];
    const float* b11   = (const float*)d_in[4];
    const float* w12   = (const float*)d_in[5];
    const float* b12   = (const float*)d_in[6];
    const float* w13   = (const float*)d_in[7];
    const float* b13   = (const float*)d_in[8];
    float* out = (float*)d_out;

    const int n = in_sizes[0];                        // N (x is [N,1])
    const int per_block = 256 * TILES;                // 4 waves x 4 tiles x 64 pts
    const int blocks = (n + per_block - 1) / per_block;
    centershift_kernel<<<blocks, 256, 0, stream>>>(
        x, pos_i, pos_j, w11, b11, w12, b12, w13, b13, out, n);
}